// Round 1
// baseline (141.842 us; speedup 1.0000x reference)
//
#include <hip/hip_runtime.h>

// Problem constants (fixed by the reference):
//   L=8 layers, H=512 units/layer, K=16 links, N_IN=512, B=8192
//   values buffer grows 512 -> 4608 cols; output = last 512 cols (fp32).
#define LAYERS 8
#define H      512
#define K      16
#define N_IN   512
#define BATCH  8192
#define R      4      // batch rows per block (float4 = 4 rows per LDS col)
#define NT     256    // threads per block
// Cols 0..4095 are gatherable (layer l gathers from [0, 512+512*l), max l=7 -> <4096).
// Layer 7's output is never gathered -> write it straight to global, LDS = exactly 64 KB.
#define LDS_COLS 4096

__global__ __launch_bounds__(NT, 2)
void ffn_fused_kernel(const float* __restrict__ x,
                      const int*   __restrict__ link_idx,
                      const float* __restrict__ weights,
                      const float* __restrict__ bias,
                      float*       __restrict__ out)
{
    // vals[c] = {values[row0+0][c], values[row0+1][c], values[row0+2][c], values[row0+3][c]}
    // One random gather = one ds_read_b128 serving 4 batch rows.
    __shared__ float4 vals[LDS_COLS];   // 65536 bytes -> 2 blocks/CU

    const int tid  = threadIdx.x;
    const int row0 = blockIdx.x * R;

    // ---- Stage x rows into LDS (coalesced global reads per r; b128 LDS writes) ----
    #pragma unroll
    for (int cc = 0; cc < N_IN / NT; ++cc) {
        const int c = cc * NT + tid;
        float4 v;
        v.x = x[(row0 + 0) * N_IN + c];
        v.y = x[(row0 + 1) * N_IN + c];
        v.z = x[(row0 + 2) * N_IN + c];
        v.w = x[(row0 + 3) * N_IN + c];
        vals[c] = v;
    }
    __syncthreads();

    // ---- Layers ----
    for (int l = 0; l < LAYERS; ++l) {
        #pragma unroll
        for (int h0 = 0; h0 < H; h0 += NT) {
            const int h    = h0 + tid;
            const int base = (l * H + h) * K;
            const int4*   ip = (const int4*)  (link_idx + base);   // 64 B/thread, coalesced
            const float4* wp = (const float4*)(weights  + base);   // 64 B/thread, coalesced
            const int4   i0 = ip[0], i1 = ip[1], i2 = ip[2], i3 = ip[3];
            const float4 w0 = wp[0], w1 = wp[1], w2 = wp[2], w3 = wp[3];
            const float  b  = bias[l * H + h];
            float4 acc = {b, b, b, b};

            // 16 independent ds_read_b128 gathers -> deep lgkmcnt pipelining
            #define GATH(ii, ww) { float4 v = vals[(ii)];              \
                acc.x = fmaf(v.x, (ww), acc.x);                        \
                acc.y = fmaf(v.y, (ww), acc.y);                        \
                acc.z = fmaf(v.z, (ww), acc.z);                        \
                acc.w = fmaf(v.w, (ww), acc.w); }
            GATH(i0.x, w0.x); GATH(i0.y, w0.y); GATH(i0.z, w0.z); GATH(i0.w, w0.w);
            GATH(i1.x, w1.x); GATH(i1.y, w1.y); GATH(i1.z, w1.z); GATH(i1.w, w1.w);
            GATH(i2.x, w2.x); GATH(i2.y, w2.y); GATH(i2.z, w2.z); GATH(i2.w, w2.w);
            GATH(i3.x, w3.x); GATH(i3.y, w3.y); GATH(i3.z, w3.z); GATH(i3.w, w3.w);
            #undef GATH

            acc.x = 1.0f / (1.0f + __expf(-acc.x));
            acc.y = 1.0f / (1.0f + __expf(-acc.y));
            acc.z = 1.0f / (1.0f + __expf(-acc.z));
            acc.w = 1.0f / (1.0f + __expf(-acc.w));

            if (l < LAYERS - 1) {
                vals[N_IN + l * H + h] = acc;        // ds_write_b128
            } else {
                // final layer: coalesced global stores (lanes -> consecutive h)
                out[(row0 + 0) * H + h] = acc.x;
                out[(row0 + 1) * H + h] = acc.y;
                out[(row0 + 2) * H + h] = acc.z;
                out[(row0 + 3) * H + h] = acc.w;
            }
        }
        if (l < LAYERS - 1) __syncthreads();
    }
}

extern "C" void kernel_launch(void* const* d_in, const int* in_sizes, int n_in,
                              void* d_out, int out_size, void* d_ws, size_t ws_size,
                              hipStream_t stream) {
    const float* x        = (const float*)d_in[0];
    const int*   link_idx = (const int*)  d_in[1];
    const float* weights  = (const float*)d_in[2];
    const float* bias     = (const float*)d_in[3];
    float*       out      = (float*)d_out;

    ffn_fused_kernel<<<dim3(BATCH / R), dim3(NT), 0, stream>>>(x, link_idx, weights, bias, out);
}

// Round 2
// 115.894 us; speedup vs baseline: 1.2239x; 1.2239x over previous
//
#include <hip/hip_runtime.h>
#include <hip/hip_fp16.h>

// L=8 layers, H=512, K=16 links, N_IN=512, B=8192; out = last 512 cols (fp32).
#define LAYERS 8
#define H      512
#define K      16
#define N_IN   512
#define BATCH  8192
#define R      8      // batch rows per block; 8 x f16 = 16 B -> one ds_read_b128 per gather
#define NT     512    // threads per block (8 waves); 2 blocks/CU -> 16 waves/CU
// Layer l gathers from cols [0, 512+512*l); max l=7 -> cols < 4096. Layer 7's
// output is never gathered -> goes straight to global. LDS = 4096*16 B = 64 KB.
#define LDS_COLS 4096

__global__ __launch_bounds__(NT, 4)
void ffn_fused_kernel(const float* __restrict__ x,
                      const int*   __restrict__ link_idx,
                      const float* __restrict__ weights,
                      const float* __restrict__ bias,
                      float*       __restrict__ out)
{
    // vals[c*R .. c*R+7] = f16 values of column c for the block's 8 batch rows.
    __shared__ __align__(16) __half vals[LDS_COLS * R];   // 65536 B -> 2 blocks/CU

    const int tid  = threadIdx.x;
    const int row0 = blockIdx.x * R;

    // ---- Stage x rows into LDS as f16 (each thread owns one column) ----
    {
        const int c = tid;                     // NT == N_IN == 512
        float v[R];
        #pragma unroll
        for (int r = 0; r < R; ++r)
            v[r] = x[(row0 + r) * N_IN + c];   // coalesced per r
        __half2 p[R / 2];
        #pragma unroll
        for (int r = 0; r < R / 2; ++r)
            p[r] = __floats2half2_rn(v[2 * r], v[2 * r + 1]);
        *(uint4*)&vals[c * R] = *(const uint4*)p;   // one ds_write_b128
    }
    __syncthreads();

    // ---- Layers (each thread owns one h; 8 batch rows in registers) ----
    for (int l = 0; l < LAYERS; ++l) {
        const int h    = tid;
        const int base = (l * H + h) * K;
        int   idx[K];
        float w[K];
        #pragma unroll
        for (int q = 0; q < 4; ++q) {
            *(int4*)  &idx[4 * q] = ((const int4*)  (link_idx + base))[q];  // 64 B coalesced
            *(float4*)&w  [4 * q] = ((const float4*)(weights  + base))[q];  // 64 B coalesced
        }
        const float b = bias[l * H + h];
        float acc[R];
        #pragma unroll
        for (int r = 0; r < R; ++r) acc[r] = b;

        #pragma unroll
        for (int k = 0; k < K; ++k) {
            // one ds_read_b128 = 8 rows of column idx[k]
            const uint4 g = *(const uint4*)&vals[idx[k] * R];
            const __half2* hp = (const __half2*)&g;
            const float wk = w[k];
            #pragma unroll
            for (int r = 0; r < R / 2; ++r) {
                const float2 f = __half22float2(hp[r]);   // folds into v_fma_mix_f32
                acc[2 * r]     = fmaf(f.x, wk, acc[2 * r]);
                acc[2 * r + 1] = fmaf(f.y, wk, acc[2 * r + 1]);
            }
        }

        #pragma unroll
        for (int r = 0; r < R; ++r)
            acc[r] = 1.0f / (1.0f + __expf(-acc[r]));

        if (l < LAYERS - 1) {
            __half2 p[R / 2];
            #pragma unroll
            for (int r = 0; r < R / 2; ++r)
                p[r] = __floats2half2_rn(acc[2 * r], acc[2 * r + 1]);
            *(uint4*)&vals[(N_IN + l * H + h) * R] = *(const uint4*)p;  // ds_write_b128
            __syncthreads();
        } else {
            // final layer: coalesced fp32 stores (lanes -> consecutive h)
            #pragma unroll
            for (int r = 0; r < R; ++r)
                out[(row0 + r) * H + h] = acc[r];
        }
    }
}

extern "C" void kernel_launch(void* const* d_in, const int* in_sizes, int n_in,
                              void* d_out, int out_size, void* d_ws, size_t ws_size,
                              hipStream_t stream) {
    const float* x        = (const float*)d_in[0];
    const int*   link_idx = (const int*)  d_in[1];
    const float* weights  = (const float*)d_in[2];
    const float* bias     = (const float*)d_in[3];
    float*       out      = (float*)d_out;

    ffn_fused_kernel<<<dim3(BATCH / R), dim3(NT), 0, stream>>>(x, link_idx, weights, bias, out);
}